// Round 2
// baseline (604.599 us; speedup 1.0000x reference)
//
#include <hip/hip_runtime.h>
#include <math.h>

#define N_ROWS 131072
#define D 512
#define BLOCKS 2048
#define WPB 4
#define NWAVES (BLOCKS * WPB)                  // 8192 waves
#define RPW (N_ROWS / NWAVES)                  // 16 rows per wave
#define EPS 1e-6f

// s_waitcnt imm (gfx9): lgkmcnt=0xF (no wait), expcnt=0x7 (no wait), vmcnt=N (bits [3:0],[15:14])
#define WAIT_VM(N) __builtin_amdgcn_s_waitcnt(0x0F70 | ((N) & 0xF) | ((((N) >> 4) & 3) << 14))
#define PIN() __builtin_amdgcn_sched_barrier(0)

// numerically stable, branchless softplus: max(x,0) + log1p(exp(-|x|))
__device__ __forceinline__ float softplusf(float x) {
    return fmaxf(x, 0.0f) + log1pf(__expf(-fabsf(x)));
}

// one pipeline slot = one row of both inputs: 4 x float4 per lane (16 VGPRs)
struct Slot { float4 a0, a1, b0, b1; };

// issue the 4 loads for row (rowBase + T); each instruction covers a contiguous 1KB wave footprint
#define ISSUE(S, T) do {                                        \
    const float* _p1 = pRow1 + (size_t)(T) * D;                 \
    const float* _p2 = pRow2 + (size_t)(T) * D;                 \
    S.a0 = *(const float4*)(_p1);                               \
    S.a1 = *(const float4*)(_p1 + 256);                         \
    S.b0 = *(const float4*)(_p2);                               \
    S.b1 = *(const float4*)(_p2 + 256);                         \
} while (0)

__device__ __forceinline__ void proc_tile(const Slot& s, int t, int lane,
                                          float& myDot, float& myS1, float& myS2) {
    float dot = s.a0.x * s.b0.x + s.a0.y * s.b0.y + s.a0.z * s.b0.z + s.a0.w * s.b0.w
              + s.a1.x * s.b1.x + s.a1.y * s.b1.y + s.a1.z * s.b1.z + s.a1.w * s.b1.w;
    float s1  = s.a0.x * s.a0.x + s.a0.y * s.a0.y + s.a0.z * s.a0.z + s.a0.w * s.a0.w
              + s.a1.x * s.a1.x + s.a1.y * s.a1.y + s.a1.z * s.a1.z + s.a1.w * s.a1.w;
    float s2  = s.b0.x * s.b0.x + s.b0.y * s.b0.y + s.b0.z * s.b0.z + s.b0.w * s.b0.w
              + s.b1.x * s.b1.x + s.b1.y * s.b1.y + s.b1.z * s.b1.z + s.b1.w * s.b1.w;
    #pragma unroll
    for (int off = 32; off > 0; off >>= 1) {
        dot += __shfl_xor(dot, off);
        s1  += __shfl_xor(s1, off);
        s2  += __shfl_xor(s2, off);
    }
    // every lane now holds the full row sums; lane t keeps this row's result
    if (lane == t) { myDot = dot; myS1 = s1; myS2 = s2; }
}

// steady-state step: issue tile TI into SI, wait so only the 3 newer tiles (12 loads) stay
// outstanding, consume tile TP from SP
#define STEP(SI, TI, SP, TP) do {                                \
    ISSUE(SI, TI); PIN(); WAIT_VM(12); PIN();                    \
    proc_tile(SP, TP, lane, myDot, myS1, myS2);                  \
} while (0)

__global__ __launch_bounds__(256, 4) void binloss_main(
    const float* __restrict__ o1, const float* __restrict__ o2,
    const int* __restrict__ target,
    float* __restrict__ sums, int* __restrict__ icnt,
    unsigned int* __restrict__ done, float* __restrict__ out) {

    __shared__ float sPos[WPB], sNeg[WPB];
    __shared__ int sCnt[WPB];

    const int lane = threadIdx.x & 63;
    const int wave = threadIdx.x >> 6;
    const int gwave = blockIdx.x * WPB + wave;
    const int rowBase = gwave * RPW;

    // lane t (t < 16) holds the target of the wave's t-th row
    const int myT = target[rowBase + (lane & (RPW - 1))];

    const float* pRow1 = o1 + (size_t)rowBase * D + lane * 4;
    const float* pRow2 = o2 + (size_t)rowBase * D + lane * 4;

    float myDot = 0.0f, myS1 = 1.0f, myS2 = 1.0f;

    Slot s0, s1_, s2_, s3;

    // prologue: fill depth-4 pipeline with tiles 0..2 (12 loads in flight)
    ISSUE(s0, 0);
    ISSUE(s1_, 1);
    ISSUE(s2_, 2);

    STEP(s3, 3,  s0, 0);
    STEP(s0, 4,  s1_, 1);
    STEP(s1_, 5, s2_, 2);
    STEP(s2_, 6, s3, 3);
    STEP(s3, 7,  s0, 4);
    STEP(s0, 8,  s1_, 5);
    STEP(s1_, 9, s2_, 6);
    STEP(s2_, 10, s3, 7);
    STEP(s3, 11, s0, 8);
    STEP(s0, 12, s1_, 9);
    STEP(s1_, 13, s2_, 10);
    STEP(s2_, 14, s3, 11);
    STEP(s3, 15, s0, 12);
    // epilogue: drain
    WAIT_VM(8);  PIN(); proc_tile(s1_, 13, lane, myDot, myS1, myS2);
    WAIT_VM(4);  PIN(); proc_tile(s2_, 14, lane, myDot, myS1, myS2);
    WAIT_VM(0);  PIN(); proc_tile(s3, 15, lane, myDot, myS1, myS2);

    // deferred per-row tail: one vectorized pass across lanes 0..15
    float d = myDot / fmaxf(sqrtf(myS1) * sqrtf(myS2), EPS);
    float posv = 0.0f, negv = 0.0f;
    int pc = 0;
    if (lane < RPW) {
        if (myT == 1) { posv = 4.0f * softplusf(-0.5f * (d - 0.5f)); pc = 1; }
        else          { negv = 0.04f * softplusf(50.0f * (d - 2.0f)); }
    }

    // wave-level reduce of the three partials
    #pragma unroll
    for (int off = 32; off > 0; off >>= 1) {
        posv += __shfl_xor(posv, off);
        negv += __shfl_xor(negv, off);
        pc   += __shfl_xor(pc, off);
    }

    if (lane == 0) { sPos[wave] = posv; sNeg[wave] = negv; sCnt[wave] = pc; }
    __syncthreads();
    if (threadIdx.x == 0) {
        float p = sPos[0] + sPos[1] + sPos[2] + sPos[3];
        float n = sNeg[0] + sNeg[1] + sNeg[2] + sNeg[3];
        int c = sCnt[0] + sCnt[1] + sCnt[2] + sCnt[3];
        atomicAdd(&sums[0], p);
        atomicAdd(&sums[1], n);
        atomicAdd(&icnt[0], c);
        __threadfence();
        unsigned int old = atomicAdd(done, 1u);
        if (old == (unsigned int)(gridDim.x - 1)) {
            __threadfence();
            float ps = __hip_atomic_load(&sums[0], __ATOMIC_RELAXED, __HIP_MEMORY_SCOPE_AGENT);
            float ns = __hip_atomic_load(&sums[1], __ATOMIC_RELAXED, __HIP_MEMORY_SCOPE_AGENT);
            int np = __hip_atomic_load(&icnt[0], __ATOMIC_RELAXED, __HIP_MEMORY_SCOPE_AGENT);
            int nn = N_ROWS - np;
            out[0] = ps / (float)(np > 1 ? np : 1) + ns / (float)(nn > 1 ? nn : 1);
        }
    }
}

extern "C" void kernel_launch(void* const* d_in, const int* in_sizes, int n_in,
                              void* d_out, int out_size, void* d_ws, size_t ws_size,
                              hipStream_t stream) {
    const float* o1 = (const float*)d_in[0];
    const float* o2 = (const float*)d_in[1];
    const int* tgt = (const int*)d_in[2];
    float* out = (float*)d_out;
    float* sums = (float*)d_ws;
    int* cnt = (int*)((char*)d_ws + 8);
    unsigned int* done = (unsigned int*)((char*)d_ws + 12);

    hipMemsetAsync(d_ws, 0, 16, stream);
    binloss_main<<<BLOCKS, 256, 0, stream>>>(o1, o2, tgt, sums, cnt, done, out);
}